// Round 5
// baseline (169.720 us; speedup 1.0000x reference)
//
#include <hip/hip_runtime.h>

#define NS 64     // samples per batch
#define D  256    // hidden dims
#define O  10     // output dim
#define TK 32     // GEMM K-chunk
#define LSTR 36   // LDS row stride for 64-row tiles (TK+4, 16B-aligned)

// ---------------- shared helper: 4-row dot blocks (A-row vs 64 B-rows) ------
__device__ __forceinline__ void dot_rows(const float* __restrict__ Arow_base,
                                         const float* __restrict__ B,
                                         float* __restrict__ dst, int n0, int t)
{
    __shared__ float as[D];
    int wave = t >> 6, lane = t & 63;
    for (int nn = 0; nn < 4; ++nn) {
        int n = n0 + nn;
        __syncthreads();
        as[t] = Arow_base[n * D + t];
        __syncthreads();
        for (int m = wave; m < NS; m += 4) {
            const float* Bv = B + m * D;
            float v = as[lane] * Bv[lane]
                    + as[64 + lane] * Bv[64 + lane]
                    + as[128 + lane] * Bv[128 + lane]
                    + as[192 + lane] * Bv[192 + lane];
            #pragma unroll
            for (int off = 32; off > 0; off >>= 1) v += __shfl_xor(v, off);
            if (lane == 0) dst[n * NS + m] = v;
        }
    }
}

// ============ A: layer-1 GEMM (128x256x256) + tanh + x-dots ================
// GEMM blocks 0..31: 32x32 tiles (4 row-groups x 8 col-groups).
// Blocks 32..47: x-dots.
__global__ __launch_bounds__(256) void fwd1_kernel(
    const float* __restrict__ x1, const float* __restrict__ x2,
    const float* __restrict__ W1, const float* __restrict__ b1,
    float* __restrict__ h1o, float* __restrict__ S1o, float* __restrict__ dots)
{
    int t = threadIdx.x;
    if (blockIdx.x >= 32) {
        dot_rows(x1, x2, dots + 0 * NS * NS, (blockIdx.x - 32) * 4, t);
        return;
    }
    int by = blockIdx.x >> 3, bx = blockIdx.x & 7;
    const float* arow = (by < 2) ? (x1 + by * 32 * D) : (x2 + (by - 2) * 32 * D);
    int col0 = bx * 32;
    __shared__ float As[32 * 36], Bs[32 * 36];
    int tx = t & 31, ty = t >> 5;

    float acc[4];
    float bv = b1[col0 + tx];
    #pragma unroll
    for (int i = 0; i < 4; ++i) acc[i] = bv;

    int r = t >> 3, c4 = t & 7;
    for (int kc = 0; kc < D; kc += TK) {
        __syncthreads();
        *(float4*)&As[r * 36 + c4 * 4] = *(const float4*)&arow[r * D + kc + c4 * 4];
        *(float4*)&Bs[r * 36 + c4 * 4] = *(const float4*)&W1[(kc + r) * D + col0 + c4 * 4];
        __syncthreads();
        #pragma unroll
        for (int g = 0; g < 8; ++g) {
            float4 a4[4];
            #pragma unroll
            for (int i = 0; i < 4; ++i)
                a4[i] = *(const float4*)&As[(ty + 8 * i) * 36 + 4 * g];
            float bb0 = Bs[(4 * g + 0) * 36 + tx];
            float bb1 = Bs[(4 * g + 1) * 36 + tx];
            float bb2 = Bs[(4 * g + 2) * 36 + tx];
            float bb3 = Bs[(4 * g + 3) * 36 + tx];
            #pragma unroll
            for (int i = 0; i < 4; ++i) {
                acc[i] = fmaf(a4[i].x, bb0, acc[i]);
                acc[i] = fmaf(a4[i].y, bb1, acc[i]);
                acc[i] = fmaf(a4[i].z, bb2, acc[i]);
                acc[i] = fmaf(a4[i].w, bb3, acc[i]);
            }
        }
    }
    #pragma unroll
    for (int i = 0; i < 4; ++i) {
        int s = by * 32 + ty + 8 * i;
        float h = tanhf(acc[i]);
        h1o[s * D + col0 + tx] = h;
        S1o[s * D + col0 + tx] = 1.0f - h * h;
    }
}

// ============ B: layer-2 GEMM + tanh + G2 build + h1-dots ==================
__global__ __launch_bounds__(256) void fwd2_kernel(
    const float* __restrict__ h1o, const float* __restrict__ W2,
    const float* __restrict__ b2, const float* __restrict__ W3,
    float* __restrict__ h2o, float* __restrict__ G2L, float* __restrict__ dots)
{
    int t = threadIdx.x;
    if (blockIdx.x >= 32) {
        dot_rows(h1o, h1o + NS * D, dots + 1 * NS * NS, (blockIdx.x - 32) * 4, t);
        return;
    }
    int by = blockIdx.x >> 3, bx = blockIdx.x & 7;
    const float* arow = h1o + by * 32 * D;
    int col0 = bx * 32;
    __shared__ float As[32 * 36], Bs[32 * 36];
    int tx = t & 31, ty = t >> 5;

    float acc[4];
    float bv = b2[col0 + tx];
    #pragma unroll
    for (int i = 0; i < 4; ++i) acc[i] = bv;

    int r = t >> 3, c4 = t & 7;
    for (int kc = 0; kc < D; kc += TK) {
        __syncthreads();
        *(float4*)&As[r * 36 + c4 * 4] = *(const float4*)&arow[r * D + kc + c4 * 4];
        *(float4*)&Bs[r * 36 + c4 * 4] = *(const float4*)&W2[(kc + r) * D + col0 + c4 * 4];
        __syncthreads();
        #pragma unroll
        for (int g = 0; g < 8; ++g) {
            float4 a4[4];
            #pragma unroll
            for (int i = 0; i < 4; ++i)
                a4[i] = *(const float4*)&As[(ty + 8 * i) * 36 + 4 * g];
            float bb0 = Bs[(4 * g + 0) * 36 + tx];
            float bb1 = Bs[(4 * g + 1) * 36 + tx];
            float bb2 = Bs[(4 * g + 2) * 36 + tx];
            float bb3 = Bs[(4 * g + 3) * 36 + tx];
            #pragma unroll
            for (int i = 0; i < 4; ++i) {
                acc[i] = fmaf(a4[i].x, bb0, acc[i]);
                acc[i] = fmaf(a4[i].y, bb1, acc[i]);
                acc[i] = fmaf(a4[i].z, bb2, acc[i]);
                acc[i] = fmaf(a4[i].w, bb3, acc[i]);
            }
        }
    }
    int col = col0 + tx;
    float w3[O];
    #pragma unroll
    for (int a = 0; a < O; ++a) w3[a] = W3[col * O + a];
    #pragma unroll
    for (int i = 0; i < 4; ++i) {
        int s = by * 32 + ty + 8 * i;
        float h = tanhf(acc[i]);
        h2o[s * D + col] = h;
        float s2 = 1.0f - h * h;
        #pragma unroll
        for (int a = 0; a < O; ++a)
            G2L[(s * O + a) * D + col] = s2 * w3[a];   // [(s,a)][i] layout
    }
}

// ============ C: backward 1280x256x256 NT GEMM + h2-dots ===================
// M1[(s,a),i] = S1[s,i] * sum_j M2[(s,a),j] * W2[i,j]
__global__ __launch_bounds__(256) void bwd_kernel(
    const float* __restrict__ G2L, const float* __restrict__ W2,
    const float* __restrict__ S1, float* __restrict__ G1L,
    const float* __restrict__ h2o, float* __restrict__ dots)
{
    int t = threadIdx.x;
    if (blockIdx.x >= 80) {
        dot_rows(h2o, h2o + NS * D, dots + 2 * NS * NS, (blockIdx.x - 80) * 4, t);
        return;
    }
    int by = blockIdx.x >> 2, bx = blockIdx.x & 3;
    __shared__ float As[64 * LSTR], Bs[64 * LSTR];
    int tx = t & 15, ty = t >> 4;
    float acc[4][4];
    #pragma unroll
    for (int i = 0; i < 4; ++i)
        #pragma unroll
        for (int j = 0; j < 4; ++j) acc[i][j] = 0.0f;

    const float* arow = G2L + (by * 64) * D;
    const float* brow = W2 + (bx * 64) * D;
    for (int kc = 0; kc < D; kc += TK) {
        __syncthreads();
        #pragma unroll
        for (int u = 0; u < 2; ++u) {
            int idx = t + u * 256;
            int r = idx >> 3, c4 = idx & 7;
            int goff = r * D + kc + c4 * 4;
            int loff = r * LSTR + c4 * 4;
            *(float4*)&As[loff] = *(const float4*)&arow[goff];
            *(float4*)&Bs[loff] = *(const float4*)&brow[goff];
        }
        __syncthreads();
        #pragma unroll
        for (int kk = 0; kk < TK; kk += 4) {
            float4 a[4], b[4];
            #pragma unroll
            for (int i = 0; i < 4; ++i)
                a[i] = *(const float4*)&As[(4 * ty + i) * LSTR + kk];
            #pragma unroll
            for (int j = 0; j < 4; ++j)
                b[j] = *(const float4*)&Bs[(tx + 16 * j) * LSTR + kk];
            #pragma unroll
            for (int i = 0; i < 4; ++i)
                #pragma unroll
                for (int j = 0; j < 4; ++j) {
                    acc[i][j] = fmaf(a[i].x, b[j].x, acc[i][j]);
                    acc[i][j] = fmaf(a[i].y, b[j].y, acc[i][j]);
                    acc[i][j] = fmaf(a[i].z, b[j].z, acc[i][j]);
                    acc[i][j] = fmaf(a[i].w, b[j].w, acc[i][j]);
                }
        }
    }
    #pragma unroll
    for (int i = 0; i < 4; ++i) {
        int R = by * 64 + 4 * ty + i;
        int s = R / O;
        #pragma unroll
        for (int j = 0; j < 4; ++j) {
            int col = bx * 64 + tx + 16 * j;
            G1L[R * D + col] = acc[i][j] * S1[s * D + col];
        }
    }
}

// ============ D: dual 640x640x256 GEMM + NTK epilogue (32x64 tiles) ========
__global__ __launch_bounds__(256) void k3_gemm_kernel(
    const float* __restrict__ G1L, const float* __restrict__ G2L,
    const float* __restrict__ dots, float* __restrict__ out)
{
    int by = blockIdx.x / 10, bx = blockIdx.x % 10;     // 20 x 10 = 200 blocks
    __shared__ float A1[32 * LSTR], B1[64 * LSTR], A2[32 * LSTR], B2[64 * LSTR];
    int t = threadIdx.x;
    int tx = t & 15, ty = t >> 4;

    float acc1[2][4], acc2[2][4];
    #pragma unroll
    for (int i = 0; i < 2; ++i)
        #pragma unroll
        for (int j = 0; j < 4; ++j) { acc1[i][j] = 0.0f; acc2[i][j] = 0.0f; }

    const float* arow1 = G1L + (by * 32) * D;
    const float* brow1 = G1L + (640 + bx * 64) * D;
    const float* arow2 = G2L + (by * 32) * D;
    const float* brow2 = G2L + (640 + bx * 64) * D;

    for (int kc = 0; kc < D; kc += TK) {
        __syncthreads();
        {
            int r = t >> 3, c4 = t & 7;
            int goff = r * D + kc + c4 * 4;
            int loff = r * LSTR + c4 * 4;
            *(float4*)&A1[loff] = *(const float4*)&arow1[goff];
            *(float4*)&A2[loff] = *(const float4*)&arow2[goff];
        }
        #pragma unroll
        for (int u = 0; u < 2; ++u) {
            int idx = t + u * 256;
            int r = idx >> 3, c4 = idx & 7;
            int goff = r * D + kc + c4 * 4;
            int loff = r * LSTR + c4 * 4;
            *(float4*)&B1[loff] = *(const float4*)&brow1[goff];
            *(float4*)&B2[loff] = *(const float4*)&brow2[goff];
        }
        __syncthreads();
        #pragma unroll
        for (int kk = 0; kk < TK; kk += 4) {
            float4 a1[2], a2[2], b1v[4], b2v[4];
            #pragma unroll
            for (int i = 0; i < 2; ++i) {
                a1[i] = *(const float4*)&A1[(2 * ty + i) * LSTR + kk];
                a2[i] = *(const float4*)&A2[(2 * ty + i) * LSTR + kk];
            }
            #pragma unroll
            for (int j = 0; j < 4; ++j) {
                b1v[j] = *(const float4*)&B1[(tx + 16 * j) * LSTR + kk];
                b2v[j] = *(const float4*)&B2[(tx + 16 * j) * LSTR + kk];
            }
            #pragma unroll
            for (int i = 0; i < 2; ++i)
                #pragma unroll
                for (int j = 0; j < 4; ++j) {
                    acc1[i][j] = fmaf(a1[i].x, b1v[j].x, acc1[i][j]);
                    acc1[i][j] = fmaf(a1[i].y, b1v[j].y, acc1[i][j]);
                    acc1[i][j] = fmaf(a1[i].z, b1v[j].z, acc1[i][j]);
                    acc1[i][j] = fmaf(a1[i].w, b1v[j].w, acc1[i][j]);
                    acc2[i][j] = fmaf(a2[i].x, b2v[j].x, acc2[i][j]);
                    acc2[i][j] = fmaf(a2[i].y, b2v[j].y, acc2[i][j]);
                    acc2[i][j] = fmaf(a2[i].z, b2v[j].z, acc2[i][j]);
                    acc2[i][j] = fmaf(a2[i].w, b2v[j].w, acc2[i][j]);
                }
        }
    }

    #pragma unroll
    for (int i = 0; i < 2; ++i) {
        int R = by * 32 + 2 * ty + i;
        int n = R / O, a = R - n * O;
        #pragma unroll
        for (int j = 0; j < 4; ++j) {
            int C = bx * 64 + tx + 16 * j;
            int m = C / O, b = C - m * O;
            float cx  = 1.0f + dots[0 * NS * NS + n * NS + m];
            float ch1 = 1.0f + dots[1 * NS * NS + n * NS + m];
            float val = cx * acc1[i][j] + ch1 * acc2[i][j];
            if (a == b) val += 1.0f + dots[2 * NS * NS + n * NS + m];
            out[(n * NS + m) * (O * O) + a * O + b] = val;
        }
    }
}

extern "C" void kernel_launch(void* const* d_in, const int* in_sizes, int n_in,
                              void* d_out, int out_size, void* d_ws, size_t ws_size,
                              hipStream_t stream) {
    const float* x1 = (const float*)d_in[0];
    const float* x2 = (const float*)d_in[1];
    const float* W1 = (const float*)d_in[2];
    const float* b1 = (const float*)d_in[3];
    const float* W2 = (const float*)d_in[4];
    const float* b2 = (const float*)d_in[5];
    const float* W3 = (const float*)d_in[6];
    // b3 (d_in[7]) does not enter the Jacobian.

    float* ws   = (float*)d_ws;
    float* h1   = ws;                     // 128*256
    float* S1   = h1 + 128 * D;           // 128*256
    float* h2   = S1 + 128 * D;           // 128*256
    float* G2L  = h2 + 128 * D;           // 1280*256  ([s*O+a][i])
    float* G1L  = G2L + 1280 * D;         // 1280*256
    float* dots = G1L + 1280 * D;         // 3*64*64
    float* out  = (float*)d_out;

    hipLaunchKernelGGL(fwd1_kernel, dim3(48), dim3(256), 0, stream,
                       x1, x2, W1, b1, h1, S1, dots);
    hipLaunchKernelGGL(fwd2_kernel, dim3(48), dim3(256), 0, stream,
                       h1, W2, b2, W3, h2, G2L, dots);
    hipLaunchKernelGGL(bwd_kernel, dim3(96), dim3(256), 0, stream,
                       G2L, W2, S1, G1L, h2, dots);
    hipLaunchKernelGGL(k3_gemm_kernel, dim3(200), dim3(256), 0, stream,
                       G1L, G2L, dots, out);
}

// Round 6
// 168.675 us; speedup vs baseline: 1.0062x; 1.0062x over previous
//
#include <hip/hip_runtime.h>

#define NS 64     // samples per batch
#define D  256    // hidden dims
#define O  10     // output dim
#define TK 32     // GEMM K-chunk
#define LSTR 36   // LDS row stride (TK+4, 16B-aligned, conflict-free)
#define NB 208    // grid size (<= 256 CUs -> all blocks co-resident)
#define MAGIC 0x13579BDFu

union SharedU {
    struct { float xs[D]; float hs[D]; } fw;                                   // 2 KB
    struct { float as[D]; } dt;                                                // 1 KB
    struct { float As[64 * LSTR]; float Bs[64 * LSTR]; } bg;                   // 18 KB
    struct { float A1[32 * LSTR]; float B1[64 * LSTR];
             float A2[32 * LSTR]; float B2[64 * LSTR]; } gm;                   // 27.6 KB
};

// device-scope software grid barrier: monotone counter, bounded spin
__device__ __forceinline__ void gsync(unsigned* cnt, unsigned target) {
    __syncthreads();
    if (threadIdx.x == 0) {
        __threadfence();                       // release: drain + L2 writeback
        atomicAdd(cnt, 1u);
        for (int it = 0; it < 200000; ++it) {  // bounded: never hangs the bench
            if (atomicAdd(cnt, 0u) >= target) break;
            __builtin_amdgcn_s_sleep(2);
        }
        __threadfence();                       // acquire: invalidate stale lines
    }
    __syncthreads();
}

__device__ __forceinline__ void dot_row(SharedU& sh, const float* __restrict__ Arow,
                                        const float* __restrict__ B,
                                        float* __restrict__ dst, int n, int t)
{
    sh.dt.as[t] = Arow[t];
    __syncthreads();
    int wave = t >> 6, lane = t & 63;
    for (int m = wave; m < NS; m += 4) {
        const float* Bv = B + m * D;
        float v = sh.dt.as[lane] * Bv[lane]
                + sh.dt.as[64 + lane] * Bv[64 + lane]
                + sh.dt.as[128 + lane] * Bv[128 + lane]
                + sh.dt.as[192 + lane] * Bv[192 + lane];
        #pragma unroll
        for (int off = 32; off > 0; off >>= 1) v += __shfl_xor(v, off);
        if (lane == 0) dst[n * NS + m] = v;
    }
    __syncthreads();
}

__global__ __launch_bounds__(256) void mega_ntk_kernel(
    const float* __restrict__ x1, const float* __restrict__ x2,
    const float* __restrict__ W1, const float* __restrict__ b1,
    const float* __restrict__ W2, const float* __restrict__ b2,
    const float* __restrict__ W3,
    float* __restrict__ h1o, float* __restrict__ S1o, float* __restrict__ h2o,
    float* __restrict__ G2L, float* __restrict__ G1L,
    float* __restrict__ dots, unsigned* __restrict__ bar,
    float* __restrict__ out)
{
    __shared__ SharedU sh;
    const int t = threadIdx.x;
    const int blk = blockIdx.x;

    // ---- self-initializing barrier state (ws is poisoned 0xAA each call) ----
    if (blk == 0 && t == 0) {
        atomicExch(&bar[1], 0u);
        __threadfence();
        atomicExch(&bar[0], MAGIC);
    }
    if (t == 0) {
        for (int it = 0; it < 200000; ++it) {
            if (atomicAdd(&bar[0], 0u) == MAGIC) break;
            __builtin_amdgcn_s_sleep(2);
        }
    }
    __syncthreads();

    // ================= Phase A: per-sample forward (0..127) | x-dots (128..191)
    if (blk < 128) {
        int s = blk;
        const float* x = (s < NS) ? (x1 + s * D) : (x2 + (s - NS) * D);
        sh.fw.xs[t] = x[t];
        __syncthreads();
        float acc = b1[t];
        #pragma unroll 8
        for (int k = 0; k < D; ++k) acc = fmaf(sh.fw.xs[k], W1[k * D + t], acc);
        float h1v = tanhf(acc);
        h1o[s * D + t] = h1v;
        S1o[s * D + t] = 1.0f - h1v * h1v;
        sh.fw.hs[t] = h1v;
        __syncthreads();
        acc = b2[t];
        #pragma unroll 8
        for (int k = 0; k < D; ++k) acc = fmaf(sh.fw.hs[k], W2[k * D + t], acc);
        float h2v = tanhf(acc);
        h2o[s * D + t] = h2v;
        float s2 = 1.0f - h2v * h2v;
        #pragma unroll
        for (int a = 0; a < O; ++a)
            G2L[(s * O + a) * D + t] = s2 * W3[t * O + a];   // [(s,a)][i] layout
    } else if (blk < 192) {
        int n = blk - 128;
        dot_row(sh, x1 + n * D, x2, dots + 0 * NS * NS, n, t);
    }

    gsync(&bar[1], NB);

    // ============ Phase B: bwd NT GEMM (0..79) | h1-dots (80..143) | h2-dots (144..207)
    if (blk < 80) {
        // G1[(s,a),i] = S1[s,i] * sum_j G2[(s,a),j] * W2[i,j]
        int by = blk >> 2, bx = blk & 3;
        int tx = t & 15, ty = t >> 4;
        float acc[4][4];
        #pragma unroll
        for (int i = 0; i < 4; ++i)
            #pragma unroll
            for (int j = 0; j < 4; ++j) acc[i][j] = 0.0f;

        const float* arow = G2L + (by * 64) * D;
        const float* brow = W2 + (bx * 64) * D;
        for (int kc = 0; kc < D; kc += TK) {
            __syncthreads();
            #pragma unroll
            for (int u = 0; u < 2; ++u) {
                int idx = t + u * 256;
                int r = idx >> 3, c4 = idx & 7;
                int goff = r * D + kc + c4 * 4;
                int loff = r * LSTR + c4 * 4;
                *(float4*)&sh.bg.As[loff] = *(const float4*)&arow[goff];
                *(float4*)&sh.bg.Bs[loff] = *(const float4*)&brow[goff];
            }
            __syncthreads();
            #pragma unroll
            for (int kk = 0; kk < TK; kk += 4) {
                float4 a[4], b[4];
                #pragma unroll
                for (int i = 0; i < 4; ++i)
                    a[i] = *(const float4*)&sh.bg.As[(4 * ty + i) * LSTR + kk];
                #pragma unroll
                for (int j = 0; j < 4; ++j)
                    b[j] = *(const float4*)&sh.bg.Bs[(tx + 16 * j) * LSTR + kk];
                #pragma unroll
                for (int i = 0; i < 4; ++i)
                    #pragma unroll
                    for (int j = 0; j < 4; ++j) {
                        acc[i][j] = fmaf(a[i].x, b[j].x, acc[i][j]);
                        acc[i][j] = fmaf(a[i].y, b[j].y, acc[i][j]);
                        acc[i][j] = fmaf(a[i].z, b[j].z, acc[i][j]);
                        acc[i][j] = fmaf(a[i].w, b[j].w, acc[i][j]);
                    }
            }
        }
        __syncthreads();
        #pragma unroll
        for (int i = 0; i < 4; ++i) {
            int R = by * 64 + 4 * ty + i;
            int s = R / O;
            #pragma unroll
            for (int j = 0; j < 4; ++j) {
                int col = bx * 64 + tx + 16 * j;
                G1L[R * D + col] = acc[i][j] * S1o[s * D + col];
            }
        }
    } else if (blk < 144) {
        int n = blk - 80;
        dot_row(sh, h1o + n * D, h1o + NS * D, dots + 1 * NS * NS, n, t);
    } else {
        int n = blk - 144;
        dot_row(sh, h2o + n * D, h2o + NS * D, dots + 2 * NS * NS, n, t);
    }

    gsync(&bar[1], 2u * NB);

    // ============ Phase C: dual 640x640x256 GEMM + NTK epilogue (0..199) =====
    if (blk < 200) {
        int by = blk / 10, bx = blk % 10;
        int tx = t & 15, ty = t >> 4;

        float acc1[2][4], acc2[2][4];
        #pragma unroll
        for (int i = 0; i < 2; ++i)
            #pragma unroll
            for (int j = 0; j < 4; ++j) { acc1[i][j] = 0.0f; acc2[i][j] = 0.0f; }

        const float* arow1 = G1L + (by * 32) * D;
        const float* brow1 = G1L + (640 + bx * 64) * D;
        const float* arow2 = G2L + (by * 32) * D;
        const float* brow2 = G2L + (640 + bx * 64) * D;

        for (int kc = 0; kc < D; kc += TK) {
            __syncthreads();
            {
                int r = t >> 3, c4 = t & 7;
                int goff = r * D + kc + c4 * 4;
                int loff = r * LSTR + c4 * 4;
                *(float4*)&sh.gm.A1[loff] = *(const float4*)&arow1[goff];
                *(float4*)&sh.gm.A2[loff] = *(const float4*)&arow2[goff];
            }
            #pragma unroll
            for (int u = 0; u < 2; ++u) {
                int idx = t + u * 256;
                int r = idx >> 3, c4 = idx & 7;
                int goff = r * D + kc + c4 * 4;
                int loff = r * LSTR + c4 * 4;
                *(float4*)&sh.gm.B1[loff] = *(const float4*)&brow1[goff];
                *(float4*)&sh.gm.B2[loff] = *(const float4*)&brow2[goff];
            }
            __syncthreads();
            #pragma unroll
            for (int kk = 0; kk < TK; kk += 4) {
                float4 a1[2], a2[2], b1v[4], b2v[4];
                #pragma unroll
                for (int i = 0; i < 2; ++i) {
                    a1[i] = *(const float4*)&sh.gm.A1[(2 * ty + i) * LSTR + kk];
                    a2[i] = *(const float4*)&sh.gm.A2[(2 * ty + i) * LSTR + kk];
                }
                #pragma unroll
                for (int j = 0; j < 4; ++j) {
                    b1v[j] = *(const float4*)&sh.gm.B1[(tx + 16 * j) * LSTR + kk];
                    b2v[j] = *(const float4*)&sh.gm.B2[(tx + 16 * j) * LSTR + kk];
                }
                #pragma unroll
                for (int i = 0; i < 2; ++i)
                    #pragma unroll
                    for (int j = 0; j < 4; ++j) {
                        acc1[i][j] = fmaf(a1[i].x, b1v[j].x, acc1[i][j]);
                        acc1[i][j] = fmaf(a1[i].y, b1v[j].y, acc1[i][j]);
                        acc1[i][j] = fmaf(a1[i].z, b1v[j].z, acc1[i][j]);
                        acc1[i][j] = fmaf(a1[i].w, b1v[j].w, acc1[i][j]);
                        acc2[i][j] = fmaf(a2[i].x, b2v[j].x, acc2[i][j]);
                        acc2[i][j] = fmaf(a2[i].y, b2v[j].y, acc2[i][j]);
                        acc2[i][j] = fmaf(a2[i].z, b2v[j].z, acc2[i][j]);
                        acc2[i][j] = fmaf(a2[i].w, b2v[j].w, acc2[i][j]);
                    }
            }
        }

        #pragma unroll
        for (int i = 0; i < 2; ++i) {
            int R = by * 32 + 2 * ty + i;
            int n = R / O, a = R - n * O;
            #pragma unroll
            for (int j = 0; j < 4; ++j) {
                int C = bx * 64 + tx + 16 * j;
                int m = C / O, b = C - m * O;
                float cx  = 1.0f + dots[0 * NS * NS + n * NS + m];
                float ch1 = 1.0f + dots[1 * NS * NS + n * NS + m];
                float val = cx * acc1[i][j] + ch1 * acc2[i][j];
                if (a == b) val += 1.0f + dots[2 * NS * NS + n * NS + m];
                out[(n * NS + m) * (O * O) + a * O + b] = val;
            }
        }
    }
}

extern "C" void kernel_launch(void* const* d_in, const int* in_sizes, int n_in,
                              void* d_out, int out_size, void* d_ws, size_t ws_size,
                              hipStream_t stream) {
    const float* x1 = (const float*)d_in[0];
    const float* x2 = (const float*)d_in[1];
    const float* W1 = (const float*)d_in[2];
    const float* b1 = (const float*)d_in[3];
    const float* W2 = (const float*)d_in[4];
    const float* b2 = (const float*)d_in[5];
    const float* W3 = (const float*)d_in[6];
    // b3 (d_in[7]) does not enter the Jacobian.

    float* ws    = (float*)d_ws;
    float* h1    = ws;                     // 128*256
    float* S1    = h1 + 128 * D;           // 128*256
    float* h2    = S1 + 128 * D;           // 128*256
    float* G2L   = h2 + 128 * D;           // 1280*256  ([s*O+a][i])
    float* G1L   = G2L + 1280 * D;         // 1280*256
    float* dots  = G1L + 1280 * D;         // 3*64*64
    unsigned* bar = (unsigned*)(dots + 3 * NS * NS + 64);  // own cacheline
    float* out   = (float*)d_out;

    hipLaunchKernelGGL(mega_ntk_kernel, dim3(NB), dim3(256), 0, stream,
                       x1, x2, W1, b1, W2, b2, W3,
                       h1, S1, h2, G2L, G1L, dots, bar, out);
}